// Round 4
// baseline (196.227 us; speedup 1.0000x reference)
//
#include <hip/hip_runtime.h>

#define T_DIM 4000
#define B_DIM 64
#define C_DIM 64
#define U_DIM 200
#define LOG2E 1.4426950408889634f
#define LN2 0.6931471805599453f

#define PAIRS 2000                 // pair tp = (t=2tp, t=2tp+1); no pad row
#define PB_BYTES (PAIRS * 800)     // 1.6 MB per batch (50 lanes x 16 B per pair)
#define NSLOT 20                   // uint4 slots per scan wave: 20 fused pairs in flight
#define CLAMP50 1.125899906842624e15f   // 2^50; fminf absorbs inf

__device__ __forceinline__ float hw_exp2(float x) { return __builtin_amdgcn_exp2f(x); }
__device__ __forceinline__ float hw_log2(float x) { return __builtin_amdgcn_logf(x); }

// DPP: zero-fill (bound_ctrl) lane permute, pure VALU. 0x138=wave_shr:1 (lane l <- l-1),
// 0x130=wave_shl:1 (lane l <- l+1).
template <int CTRL>
__device__ __forceinline__ int dpp_i(int x) {
    return __builtin_amdgcn_update_dpp(0, x, CTRL, 0xF, 0xF, true);
}
template <int CTRL>
__device__ __forceinline__ float dpp_f(float x) {
    return __uint_as_float((unsigned)dpp_i<CTRL>((int)__float_as_uint(x)));
}

__device__ __forceinline__ unsigned rne_bf16(float v) {   // RNE bf16 in hi16
    unsigned b = __float_as_uint(v);
    return b + 0x7FFFu + ((b >> 16) & 1u);
}

// ---------------- prep: coalesced stage -> LDS exp2 tile -> F/G emit + row-lse ----------------
// Block = (bg 0..7, tc 0..249): batches 8bg..8bg+7, rows t = 16tc..16tc+15 = pairs 8tc..8tc+7.
// Per pair/lane, eg stores FUSED-PAIR coefficients (not raw e's):
//   F_r = e_r^{t1} * e_r^{t0}   (w.x: F0,F1  w.y: F2,F3)
//   G_r = e_r^{t1} * e_{r-1}^{t0}  with u-1's class (w.z: G0,G1  w.w: G2,G3)
__global__ __launch_bounds__(256) void prep_kernel(const float* __restrict__ in,
                                                   const int* __restrict__ tgt,
                                                   unsigned* __restrict__ eg,
                                                   float* __restrict__ out) {
    __shared__ float ex[16 * 8 * 68];   // 68-stride pad (16B-aligned rows, spread banks)
    __shared__ unsigned tgc[400];       // uchar4-packed targets for 8 batches
    __shared__ float red[4];
    const int tid = threadIdx.x;
    const int bg = blockIdx.x & 7;
    const int tc = blockIdx.x >> 3;
    const int t0 = tc * 16, b0 = bg * 8;

    // stage targets (each uint = 4 consecutive u's of one batch)
    for (int o = tid; o < 400; o += 256) {
        int4 tv = ((const int4*)tgt)[bg * 400 + o];
        tgc[o] = (unsigned)(tv.x & 63) | ((unsigned)(tv.y & 63) << 8)
               | ((unsigned)(tv.z & 63) << 16) | ((unsigned)(tv.w & 63) << 24);
    }
    // stage 16 t x 8 b x 64 c, coalesced float4, exp2 in flight
    #pragma unroll
    for (int k = 0; k < 8; ++k) {
        int flat = k * 256 + tid;              // 0..2047
        int t_l = flat >> 7, i = flat & 127, b_l = i >> 4, q = i & 15;
        float4 v = *(const float4*)(in + (size_t)(t0 + t_l) * 4096 + (b0 + b_l) * 64 + q * 4);
        float4 e;
        e.x = hw_exp2(v.x * LOG2E); e.y = hw_exp2(v.y * LOG2E);
        e.z = hw_exp2(v.z * LOG2E); e.w = hw_exp2(v.w * LOG2E);
        *(float4*)&ex[(t_l * 8 + b_l) * 68 + q * 4] = e;
    }
    __syncthreads();

    // row-lse: threads 0..127 each own one (t,b) row; covers every t (incl. t=0)
    {
        float v = 0.0f;
        if (tid < 128) {
            const float4* p = (const float4*)&ex[tid * 68];
            float s = 0.0f;
            #pragma unroll
            for (int j = 0; j < 16; ++j) { float4 a = p[j]; s += (a.x + a.y) + (a.z + a.w); }
            v = hw_log2(s);
        }
        #pragma unroll
        for (int o = 32; o > 0; o >>= 1) v += __shfl_xor(v, o);
        if ((tid & 63) == 0) red[tid >> 6] = v;
    }

    // emit: 8 pairs x 8 b x 50 l = 3200 uint4; coalesced stores, LDS gathers
    for (int it = 0; it < 13; ++it) {
        int o = it * 256 + tid;
        if (o < 3200) {
            int l = o % 50;
            int rest = o / 50;                 // 0..63
            int b_l = rest & 7, tp_l = rest >> 3;
            unsigned tw = tgc[b_l * 50 + l];
            int c0 = tw & 255, c1 = (tw >> 8) & 255, c2 = (tw >> 16) & 255, c3 = tw >> 24;
            // class of u = 4l-1 (last u of previous quad); l==0: dummy (term is zeroed by dpp)
            int cm1 = l ? (int)(tgc[b_l * 50 + l - 1] >> 24) : c0;
            const float* plo = &ex[(tp_l * 16 + b_l) * 68];   // t = 2*tp_l (local) -> e^{t0}
            const float* phi = plo + 8 * 68;                  // t = 2*tp_l + 1    -> e^{t1}
            float a0 = plo[c0], a1 = plo[c1], a2 = plo[c2], a3 = plo[c3], am = plo[cm1];
            float b0v = phi[c0], b1v = phi[c1], b2v = phi[c2], b3v = phi[c3];
            uint4 w;
            w.x = (rne_bf16(b0v * a0) >> 16) | (rne_bf16(b1v * a1) & 0xFFFF0000u);  // F0,F1
            w.y = (rne_bf16(b2v * a2) >> 16) | (rne_bf16(b3v * a3) & 0xFFFF0000u);  // F2,F3
            w.z = (rne_bf16(b0v * am) >> 16) | (rne_bf16(b1v * a0) & 0xFFFF0000u);  // G0,G1
            w.w = (rne_bf16(b2v * a1) >> 16) | (rne_bf16(b3v * a2) & 0xFFFF0000u);  // G2,G3
            *(uint4*)((char*)eg + (size_t)(b0 + b_l) * PB_BYTES
                      + (size_t)(tc * 8 + tp_l) * 800 + l * 16) = w;
        }
    }
    __syncthreads();
    if (tid == 0)
        atomicAdd(out, (red[0] + red[1] + red[2] + red[3]) * (LN2 / 64.0f));
}

// ---- single-step scan cores (proven baseline; boundary steps + fallback) ----
struct ScanState { float A0, A1, A2, A3; int S, D; };

__device__ __forceinline__ void renorm(ScanState& st, int lane) {
    float m = fmaxf(fmaxf(st.A0, st.A1), fmaxf(st.A2, st.A3));
    int e = (int)((__float_as_uint(m) >> 23) & 0xFFu);
    int cand = st.S + e - 127;
    int snb = dpp_i<0x138>(st.S);
    if (lane == 0) snb = -(1 << 28);
    int snew = max(cand, snb);
    int k = st.S - snew;
    st.A0 = ldexpf(st.A0, k);
    st.A1 = ldexpf(st.A1, k);
    st.A2 = ldexpf(st.A2, k);
    st.A3 = ldexpf(st.A3, k);
    st.S = snew;
    st.D = min(dpp_i<0x138>(snew) - snew, 60);
}

__device__ __forceinline__ void step(ScanState& st, float e0, float e1, float e2, float e3) {
    float sh = ldexpf(dpp_f<0x138>(st.A3), st.D);
    sh = fminf(sh, CLAMP50);
    float t0 = st.A0 + sh;
    float t1 = st.A1 + st.A0;
    float t2 = st.A2 + st.A1;
    float t3 = st.A3 + st.A2;
    st.A0 = e0 * t0; st.A1 = e1 * t1; st.A2 = e2 * t2; st.A3 = e3 * t3;
}

__device__ __forceinline__ void brenorm(ScanState& st) {
    float m = fmaxf(fmaxf(st.A0, st.A1), fmaxf(st.A2, st.A3));
    int e = (int)((__float_as_uint(m) >> 23) & 0xFFu);
    int cand = st.S + e - 127;
    int snb = dpp_i<0x130>(st.S);                  // lane63 gets 0 (junk side, harmless)
    int snew = max(cand, snb);
    int k = st.S - snew;
    st.A0 = ldexpf(st.A0, k);
    st.A1 = ldexpf(st.A1, k);
    st.A2 = ldexpf(st.A2, k);
    st.A3 = ldexpf(st.A3, k);
    st.S = snew;
    st.D = min(dpp_i<0x130>(snew) - snew, 60);
}

__device__ __forceinline__ void bstep(ScanState& st, float e0, float e1, float e2, float e3) {
    float e4s = fminf(ldexpf(dpp_f<0x130>(e0), st.D), CLAMP50);
    float b0n = dpp_f<0x130>(st.A0);
    float g0 = e0 * st.A0, g1 = e1 * st.A1, g2 = e2 * st.A2, g3 = e3 * st.A3;
    st.A0 = g0 + g1; st.A1 = g1 + g2; st.A2 = g2 + g3; st.A3 = g3 + e4s * b0n;
}

__device__ __forceinline__ ScanState scan_init(const float* in, const int* tgt, int lane, int b) {
    float v0 = in[b * 64 + (tgt[b * U_DIM] & 63)];
    ScanState st;
    st.A0 = (lane == 0) ? hw_exp2(v0 * LOG2E) : 0.0f;
    st.A1 = 0.0f; st.A2 = 0.0f; st.A3 = 0.0f;
    st.S = 0; st.D = 0;
    return st;
}

#define LO(x) __uint_as_float((x) << 16)
#define HI(x) __uint_as_float((x) & 0xFFFF0000u)

// ---- fused-pair cores: one update per t-pair, loop-carried chain = 2-3 levels ----
// Forward: A_r' = F_r*(A_r + A_{r-1}) + G_r*(A_{r-1} + A_{r-2})
//   A_{-1}, A_{-2} = prev lane's A3, A2, scaled into own S by ldexp(., D).
__device__ __forceinline__ void fstep2(ScanState& st, const uint4& w) {
    float F0 = LO(w.x), F1 = HI(w.x), F2 = LO(w.y), F3 = HI(w.y);
    float G0 = LO(w.z), G1 = HI(w.z), G2 = LO(w.w), G3 = HI(w.w);
    float sh3 = fminf(ldexpf(dpp_f<0x138>(st.A3), st.D), CLAMP50);
    float sh2 = fminf(ldexpf(dpp_f<0x138>(st.A2), st.D), CLAMP50);
    float sm1 = sh3 + sh2;
    float s0 = st.A0 + sh3;
    float s1 = st.A1 + st.A0;
    float s2 = st.A2 + st.A1;
    float s3 = st.A3 + st.A2;
    st.A0 = F0 * s0 + G0 * sm1;
    st.A1 = F1 * s1 + G1 * s0;
    st.A2 = F2 * s2 + G2 * s1;
    st.A3 = F3 * s3 + G3 * s2;
}

// Backward (applies t1 then t0): B_r' = F_r*B_r + (F_{r+1}+G_{r+1})*B_{r+1} + G_{r+2}*B_{r+2}
//   G_{r+2} for r=2,3 is exactly the NEXT lane's stored G0/G1 (prep used the true u-1 class);
//   B_4, B_5 = next lane's B0, B1 scaled by ldexp(., D). Lanes >=50 hold zero state, so the
//   junk-lane coefficients never contribute.
__device__ __forceinline__ void bstep2(ScanState& st, const uint4& w) {
    float F0 = LO(w.x), F1 = HI(w.x), F2 = LO(w.y), F3 = HI(w.y);
    float G1 = HI(w.z), G2 = LO(w.w), G3 = HI(w.w);
    float nF0 = dpp_f<0x130>(LO(w.x));
    float nG0 = dpp_f<0x130>(LO(w.z));
    float nG1 = dpp_f<0x130>(HI(w.z));
    float nB0 = fminf(ldexpf(dpp_f<0x130>(st.A0), st.D), CLAMP50);
    float nB1 = fminf(ldexpf(dpp_f<0x130>(st.A1), st.D), CLAMP50);
    float H0 = F1 + G1, H1 = F2 + G2, H2 = F3 + G3, H3 = nF0 + nG0;
    float n0 = F0 * st.A0 + H0 * st.A1 + G2 * st.A2;
    float n1 = F1 * st.A1 + H1 * st.A2 + G3 * st.A3;
    float n2 = F2 * st.A2 + H2 * st.A3 + nG0 * nB0;
    float n3 = F3 * st.A3 + H3 * nB0  + nG1 * nB1;
    st.A0 = n0; st.A1 = n1; st.A2 = n2; st.A3 = n3;
}

// boundary single-step e's gathered straight from inputs (t in {1, 2000, 2001})
__device__ __forceinline__ float4 raw_e(const float* in, int b, int t,
                                        int c0, int c1, int c2, int c3) {
    const float* row = in + ((size_t)t * B_DIM + b) * C_DIM;
    float4 e;
    e.x = hw_exp2(row[c0] * LOG2E);
    e.y = hw_exp2(row[c1] * LOG2E);
    e.z = hw_exp2(row[c2] * LOG2E);
    e.w = hw_exp2(row[c3] * LOG2E);
    return e;
}

// Meet-in-the-middle scan: block b has wave0 = forward (t=1..2000), wave1 = backward
// (t=3999..2001); junction dot-product + wave-lse in-block. Each wb slot is one FUSED
// t-pair; renorm cadence per j identical to the proven 2-step baseline.
__global__ __launch_bounds__(128, 1) void scan2_kernel(const float* __restrict__ in,
                                                       const int* __restrict__ tgt,
                                                       const unsigned* __restrict__ eg,
                                                       float* __restrict__ out) {
    __shared__ float jb0[64], jb1[64], jb2[64], jb3[64];
    __shared__ int jsb[64];
    const int lane = threadIdx.x & 63;
    const int wv = threadIdx.x >> 6;
    const int b = blockIdx.x;
    const int lidx = (lane < 50) ? lane : 49;
    const char* egb = (const char*)eg + (size_t)b * PB_BYTES;

    int4 tg = ((const int4*)(tgt + b * U_DIM))[lidx];
    tg.x &= 63; tg.y &= 63; tg.z &= 63; tg.w &= 63;

    ScanState st;
    if (wv == 1) {
        // ---------- backward: beta = e_199; fused pairs 1999..1001, then t=2001 single ----------
        st.A0 = 0.0f; st.A1 = 0.0f; st.A2 = 0.0f;
        st.A3 = (lane == 49) ? 1.0f : 0.0f;
        st.S = 0; st.D = 0;
        int off = 1999 * 800 + lidx * 16;
        uint4 wb[NSLOT];
        #pragma unroll
        for (int j = 0; j < NSLOT; ++j) { wb[j] = *(const uint4*)(egb + off); off -= 800; }
        for (int k = 0; k < 49; ++k) {
            #pragma unroll
            for (int j = 0; j < NSLOT; ++j) {
                if ((j & 3) == 0) brenorm(st);
                uint4 w = wb[j];
                wb[j] = *(const uint4*)(egb + off); off -= 800;
                bstep2(st, w);
            }
        }
        #pragma unroll
        for (int j = 0; j < NSLOT - 1; ++j) {   // pairs 1019..1001 fused
            if ((j & 3) == 0) brenorm(st);
            bstep2(st, wb[j]);
        }
        {   // pair 1000 hi-only: t = 2001 from raw inputs
            float4 e = raw_e(in, b, 2001, tg.x, tg.y, tg.z, tg.w);
            bstep(st, e.x, e.y, e.z, e.w);
        }
        brenorm(st);
        jb0[lane] = st.A0; jb1[lane] = st.A1; jb2[lane] = st.A2; jb3[lane] = st.A3;
        jsb[lane] = st.S;
    } else {
        // ---------- forward: alpha_0 -> t=1 single -> fused pairs 1..999 -> t=2000 single ----------
        st = scan_init(in, tgt, lane, b);
        {   // t = 1 (hi of pair 0) from raw inputs; st.D == 0 and A's are 0/lane0-only
            float4 e = raw_e(in, b, 1, tg.x, tg.y, tg.z, tg.w);
            step(st, e.x, e.y, e.z, e.w);
        }
        int off = 800 + lidx * 16;
        uint4 wb[NSLOT];
        #pragma unroll
        for (int j = 0; j < NSLOT; ++j) { wb[j] = *(const uint4*)(egb + off); off += 800; }
        for (int k = 0; k < 49; ++k) {
            #pragma unroll
            for (int j = 0; j < NSLOT; ++j) {
                if ((j & 3) == 0) renorm(st, lane);
                uint4 w = wb[j];
                wb[j] = *(const uint4*)(egb + off); off += 800;
                fstep2(st, w);
            }
        }
        #pragma unroll
        for (int j = 0; j < NSLOT - 1; ++j) {   // pairs 981..999 fused
            if ((j & 3) == 0) renorm(st, lane);
            fstep2(st, wb[j]);
        }
        {   // pair 1000 lo-only: t = 2000 from raw inputs
            float4 e = raw_e(in, b, 2000, tg.x, tg.y, tg.z, tg.w);
            step(st, e.x, e.y, e.z, e.w);
        }
        renorm(st, lane);
    }
    __syncthreads();
    if (wv == 0) {
        // junction: log2( sum_u alpha_2000[u] * beta_2001[u] )
        float d = st.A0 * jb0[lane] + st.A1 * jb1[lane]
                + st.A2 * jb2[lane] + st.A3 * jb3[lane];
        float ll = (lane < 50) ? hw_log2(fmaxf(d, 1e-38f)) + (float)(st.S + jsb[lane])
                               : -1e30f;
        float mx = ll;
        #pragma unroll
        for (int o = 32; o > 0; o >>= 1) mx = fmaxf(mx, __shfl_xor(mx, o));
        float s = (lane < 50) ? hw_exp2(ll - mx) : 0.0f;
        #pragma unroll
        for (int o = 32; o > 0; o >>= 1) s += __shfl_xor(s, o);
        if (lane == 0) atomicAdd(out, -(mx + hw_log2(s)) * (LN2 / 64.0f));
    }
}

// ---- fallback pair (no-workspace path; R7-proven forward core) ----
__global__ __launch_bounds__(256) void lse_sum_kernel(const float* __restrict__ in,
                                                      float* __restrict__ out) {
    const int lane = threadIdx.x & 63;
    const int w = threadIdx.x >> 6;
    const int wid = blockIdx.x * 4 + w;
    const int ROWS = (T_DIM * B_DIM) / 1024;
    const float* p = in + (size_t)wid * ROWS * 64 + lane;
    float acc = 0.0f;
    for (int i = 0; i < ROWS; i += 2) {
        float xa = p[(size_t)i * 64];
        float xb = p[(size_t)(i + 1) * 64];
        float ea = hw_exp2(xa * LOG2E);
        float eb = hw_exp2(xb * LOG2E);
        #pragma unroll
        for (int off = 32; off > 0; off >>= 1) {
            ea += __shfl_xor(ea, off);
            eb += __shfl_xor(eb, off);
        }
        acc += hw_log2(ea) + hw_log2(eb);
    }
    __shared__ float red[4];
    if (lane == 0) red[w] = acc;
    __syncthreads();
    if (threadIdx.x == 0)
        atomicAdd(out, (red[0] + red[1] + red[2] + red[3]) * (LN2 / 64.0f));
}

__global__ __launch_bounds__(64) void scan_fb(const float* __restrict__ in,
                                              const int* __restrict__ tgt,
                                              float* __restrict__ out) {
    const int lane = threadIdx.x;
    const int b = blockIdx.x;
    const int lidx = (lane < 50) ? lane : 49;
    int4 tg = ((const int4*)(tgt + b * U_DIM))[lidx];
    tg.x &= 63; tg.y &= 63; tg.z &= 63; tg.w &= 63;
    ScanState st = scan_init(in, tgt, lane, b);
    const char* inb = (const char*)in;
    int o0 = 16384 + b * 256 + tg.x * 4;
    int o1 = 16384 + b * 256 + tg.y * 4;
    int o2 = 16384 + b * 256 + tg.z * 4;
    int o3 = 16384 + b * 256 + tg.w * 4;
    const int m0 = 3999 * 16384 + b * 256 + tg.x * 4;
    const int m1 = m0 + (tg.y - tg.x) * 4;
    const int m2 = m0 + (tg.z - tg.x) * 4;
    const int m3 = m0 + (tg.w - tg.x) * 4;
    float f0[16], f1[16], f2[16], f3[16];
    #pragma unroll
    for (int j = 0; j < 16; ++j) {
        f0[j] = *(const float*)(inb + min(o0, m0)); o0 += 16384;
        f1[j] = *(const float*)(inb + min(o1, m1)); o1 += 16384;
        f2[j] = *(const float*)(inb + min(o2, m2)); o2 += 16384;
        f3[j] = *(const float*)(inb + min(o3, m3)); o3 += 16384;
    }
    for (int k = 0; k < 249; ++k) {
        #pragma unroll
        for (int j = 0; j < 16; ++j) {
            if (j == 0 || j == 8) renorm(st, lane);
            float e0 = hw_exp2(f0[j] * LOG2E);
            float e1 = hw_exp2(f1[j] * LOG2E);
            float e2 = hw_exp2(f2[j] * LOG2E);
            float e3 = hw_exp2(f3[j] * LOG2E);
            f0[j] = *(const float*)(inb + min(o0, m0)); o0 += 16384;
            f1[j] = *(const float*)(inb + min(o1, m1)); o1 += 16384;
            f2[j] = *(const float*)(inb + min(o2, m2)); o2 += 16384;
            f3[j] = *(const float*)(inb + min(o3, m3)); o3 += 16384;
            step(st, e0, e1, e2, e3);
        }
    }
    #pragma unroll
    for (int j = 0; j < 15; ++j) {
        if (j == 0 || j == 8) renorm(st, lane);
        float e0 = hw_exp2(f0[j] * LOG2E);
        float e1 = hw_exp2(f1[j] * LOG2E);
        float e2 = hw_exp2(f2[j] * LOG2E);
        float e3 = hw_exp2(f3[j] * LOG2E);
        step(st, e0, e1, e2, e3);
    }
    if (lane == 49) {
        float a2 = hw_log2(fmaxf(st.A3, 1e-38f)) + (float)st.S;
        atomicAdd(out, -a2 * (LN2 / 64.0f));
    }
}

extern "C" void kernel_launch(void* const* d_in, const int* in_sizes, int n_in,
                              void* d_out, int out_size, void* d_ws, size_t ws_size,
                              hipStream_t stream) {
    const float* inputs = (const float*)d_in[0];   // (T, B, C) fp32
    const int* targets = (const int*)d_in[1];      // (B, U) int32
    float* out = (float*)d_out;                    // scalar fp32

    (void)hipMemsetAsync(out, 0, sizeof(float), stream);

    const size_t eg_bytes = (size_t)B_DIM * PB_BYTES;   // 102.4 MB
    if (ws_size >= eg_bytes) {
        unsigned* eg = (unsigned*)d_ws;
        prep_kernel<<<2000, 256, 0, stream>>>(inputs, targets, eg, out);
        scan2_kernel<<<B_DIM, 128, 0, stream>>>(inputs, targets, eg, out);
    } else {
        scan_fb<<<B_DIM, 64, 0, stream>>>(inputs, targets, out);
        lse_sum_kernel<<<256, 256, 0, stream>>>(inputs, out);
    }
}

// Round 5
// 189.760 us; speedup vs baseline: 1.0341x; 1.0341x over previous
//
#include <hip/hip_runtime.h>

#define T_DIM 4000
#define B_DIM 64
#define C_DIM 64
#define U_DIM 200
#define LOG2E 1.4426950408889634f
#define LN2 0.6931471805599453f

#define PAIRS 2000                 // pair tp = (t=2tp, t=2tp+1); no pad row
#define PB_BYTES (PAIRS * 800)     // 1.6 MB per batch (50 lanes x 16 B per pair)
#define NSLOT 20                   // uint4 slots per scan wave: 40 steps in flight

__device__ __forceinline__ float hw_exp2(float x) { return __builtin_amdgcn_exp2f(x); }
__device__ __forceinline__ float hw_log2(float x) { return __builtin_amdgcn_logf(x); }

// DPP: zero-fill (bound_ctrl) lane permute, pure VALU. 0x138=wave_shr:1 (lane l <- l-1),
// 0x130=wave_shl:1 (lane l <- l+1).
template <int CTRL>
__device__ __forceinline__ int dpp_i(int x) {
    return __builtin_amdgcn_update_dpp(0, x, CTRL, 0xF, 0xF, true);
}
template <int CTRL>
__device__ __forceinline__ float dpp_f(float x) {
    return __uint_as_float((unsigned)dpp_i<CTRL>((int)__float_as_uint(x)));
}

__device__ __forceinline__ unsigned rne_bf16(float v) {   // RNE bf16 in hi16
    unsigned b = __float_as_uint(v);
    return b + 0x7FFFu + ((b >> 16) & 1u);
}

// ---------------- prep: coalesced stage -> bf16 LDS tile -> Eg emit + row-lse ----------------
// Block = (bg 0..7, tc 0..249): batches 8bg..8bg+7, rows t = 16tc..16tc+15 = pairs 8tc..8tc+7.
// LDS tile stores bf16 hi-bits (rounded ONCE at stage); eg bits identical to the proven
// fp32-tile pipeline since (rne>>16) repacked == rne & 0xFFFF0000 composition.
// LDS: 16*8*68 u16 = 17.4 KB (+tgc) -> 8 blocks/CU (was 4 with fp32 tile).
__global__ __launch_bounds__(256, 8) void prep_kernel(const float* __restrict__ in,
                                                      const int* __restrict__ tgt,
                                                      unsigned* __restrict__ eg,
                                                      float* __restrict__ out) {
    __shared__ unsigned short exh[16 * 8 * 68];   // bf16 hi16, 68-stride pad
    __shared__ unsigned tgc[400];                 // uchar4-packed targets for 8 batches
    __shared__ float red[4];
    const int tid = threadIdx.x;
    const int bg = blockIdx.x & 7;
    const int tc = blockIdx.x >> 3;
    const int t0 = tc * 16, b0 = bg * 8;

    // stage targets (each uint = 4 consecutive u's of one batch)
    for (int o = tid; o < 400; o += 256) {
        int4 tv = ((const int4*)tgt)[bg * 400 + o];
        tgc[o] = (unsigned)(tv.x & 63) | ((unsigned)(tv.y & 63) << 8)
               | ((unsigned)(tv.z & 63) << 16) | ((unsigned)(tv.w & 63) << 24);
    }
    // stage 16 t x 8 b x 64 c, coalesced float4, exp2+bf16-round in flight
    #pragma unroll
    for (int k = 0; k < 8; ++k) {
        int flat = k * 256 + tid;              // 0..2047
        int t_l = flat >> 7, i = flat & 127, b_l = i >> 4, q = i & 15;
        float4 v = *(const float4*)(in + (size_t)(t0 + t_l) * 4096 + (b0 + b_l) * 64 + q * 4);
        unsigned ex0 = rne_bf16(hw_exp2(v.x * LOG2E));
        unsigned ex1 = rne_bf16(hw_exp2(v.y * LOG2E));
        unsigned ex2 = rne_bf16(hw_exp2(v.z * LOG2E));
        unsigned ex3 = rne_bf16(hw_exp2(v.w * LOG2E));
        uint2 pk;
        pk.x = (ex0 >> 16) | (ex1 & 0xFFFF0000u);
        pk.y = (ex2 >> 16) | (ex3 & 0xFFFF0000u);
        *(uint2*)&exh[(t_l * 8 + b_l) * 68 + q * 4] = pk;
    }
    __syncthreads();

    // row-lse: threads 0..127 each own one (t,b) row (bf16-rounded e's; error << bf16-out ulp)
    {
        float v = 0.0f;
        if (tid < 128) {
            const unsigned* p = (const unsigned*)&exh[tid * 68];
            float s = 0.0f;
            #pragma unroll
            for (int j = 0; j < 32; ++j) {
                unsigned u = p[j];
                s += __uint_as_float(u << 16) + __uint_as_float(u & 0xFFFF0000u);
            }
            v = hw_log2(s);
        }
        #pragma unroll
        for (int o = 32; o > 0; o >>= 1) v += __shfl_xor(v, o);
        if ((tid & 63) == 0) red[tid >> 6] = v;
    }

    // emit: wave-uniform (b_l,tp_l) slots, lanes 0..49 = l. 16 slots per wave, no div/mod;
    // per item: 1 tgc read + 8 u16 LDS reads + 4 shift/or + contiguous 800B wave store.
    {
        const int wv4 = tid >> 6;      // wave 0..3
        const int ln = tid & 63;
        for (int r = wv4; r < 64; r += 4) {
            int b_l = r & 7, tp_l = r >> 3;
            if (ln < 50) {
                unsigned tw = tgc[b_l * 50 + ln];
                int c0 = tw & 255, c1 = (tw >> 8) & 255, c2 = (tw >> 16) & 255, c3 = tw >> 24;
                const unsigned short* plo = &exh[(tp_l * 16 + b_l) * 68];   // t = 2*tp_l
                const unsigned short* phi = plo + 8 * 68;                   // t = 2*tp_l + 1
                uint4 w;
                w.x = (unsigned)plo[c0] | ((unsigned)plo[c1] << 16);
                w.y = (unsigned)plo[c2] | ((unsigned)plo[c3] << 16);
                w.z = (unsigned)phi[c0] | ((unsigned)phi[c1] << 16);
                w.w = (unsigned)phi[c2] | ((unsigned)phi[c3] << 16);
                *(uint4*)((char*)eg + (size_t)(b0 + b_l) * PB_BYTES
                          + (size_t)(tc * 8 + tp_l) * 800 + ln * 16) = w;
            }
        }
    }
    __syncthreads();
    if (tid == 0)
        atomicAdd(out, (red[0] + red[1] + red[2] + red[3]) * (LN2 / 64.0f));
}

// ---- forward scan core (R0-proven, absmax 0.0) ----
struct ScanState { float A0, A1, A2, A3; int S, D; };

__device__ __forceinline__ void renorm(ScanState& st, int lane) {
    float m = fmaxf(fmaxf(st.A0, st.A1), fmaxf(st.A2, st.A3));
    int e = (int)((__float_as_uint(m) >> 23) & 0xFFu);
    int cand = st.S + e - 127;
    int snb = dpp_i<0x138>(st.S);
    if (lane == 0) snb = -(1 << 28);
    int snew = max(cand, snb);
    int k = st.S - snew;
    st.A0 = ldexpf(st.A0, k);
    st.A1 = ldexpf(st.A1, k);
    st.A2 = ldexpf(st.A2, k);
    st.A3 = ldexpf(st.A3, k);
    st.S = snew;
    st.D = min(dpp_i<0x138>(snew) - snew, 60);
}

__device__ __forceinline__ void step(ScanState& st, float e0, float e1, float e2, float e3) {
    float sh = ldexpf(dpp_f<0x138>(st.A3), st.D);
    sh = fminf(sh, 1.125899906842624e15f);         // 2^50; fminf absorbs inf
    float t0 = st.A0 + sh;
    float t1 = st.A1 + st.A0;
    float t2 = st.A2 + st.A1;
    float t3 = st.A3 + st.A2;
    st.A0 = e0 * t0; st.A1 = e1 * t1; st.A2 = e2 * t2; st.A3 = e3 * t3;
}

// ---- backward core: beta^T <- beta^T M_t; cross-lane term from lane l+1 via 0x130 ----
__device__ __forceinline__ void brenorm(ScanState& st) {
    float m = fmaxf(fmaxf(st.A0, st.A1), fmaxf(st.A2, st.A3));
    int e = (int)((__float_as_uint(m) >> 23) & 0xFFu);
    int cand = st.S + e - 127;
    int snb = dpp_i<0x130>(st.S);                  // lane63 gets 0 (junk side, harmless)
    int snew = max(cand, snb);
    int k = st.S - snew;
    st.A0 = ldexpf(st.A0, k);
    st.A1 = ldexpf(st.A1, k);
    st.A2 = ldexpf(st.A2, k);
    st.A3 = ldexpf(st.A3, k);
    st.S = snew;
    st.D = min(dpp_i<0x130>(snew) - snew, 60);
}

__device__ __forceinline__ void bstep(ScanState& st, float e0, float e1, float e2, float e3) {
    // newB_r = E_r B_r + E_{r+1} B_{r+1}; r=3 cross term = (E0 B0) of lane l+1,
    // built from dpp(e0) (off the serial chain) and dpp(B0).
    float e4s = fminf(ldexpf(dpp_f<0x130>(e0), st.D), 1.125899906842624e15f);
    float b0n = dpp_f<0x130>(st.A0);
    float g0 = e0 * st.A0, g1 = e1 * st.A1, g2 = e2 * st.A2, g3 = e3 * st.A3;
    st.A0 = g0 + g1; st.A1 = g1 + g2; st.A2 = g2 + g3; st.A3 = g3 + e4s * b0n;
}

__device__ __forceinline__ ScanState scan_init(const float* in, const int* tgt, int lane, int b) {
    float v0 = in[b * 64 + (tgt[b * U_DIM] & 63)];
    ScanState st;
    st.A0 = (lane == 0) ? hw_exp2(v0 * LOG2E) : 0.0f;
    st.A1 = 0.0f; st.A2 = 0.0f; st.A3 = 0.0f;
    st.S = 0; st.D = 0;
    return st;
}

#define LO(x) __uint_as_float((x) << 16)
#define HI(x) __uint_as_float((x) & 0xFFFF0000u)

// Meet-in-the-middle scan: block b has wave0 = forward (t=1..2000), wave1 = backward
// (t=3999..2001); junction dot-product + wave-lse in-block.
__global__ __launch_bounds__(128, 1) void scan2_kernel(const float* __restrict__ in,
                                                       const int* __restrict__ tgt,
                                                       const unsigned* __restrict__ eg,
                                                       float* __restrict__ out) {
    __shared__ float jb0[64], jb1[64], jb2[64], jb3[64];
    __shared__ int jsb[64];
    const int lane = threadIdx.x & 63;
    const int wv = threadIdx.x >> 6;
    const int b = blockIdx.x;
    const int lidx = (lane < 50) ? lane : 49;
    const char* egb = (const char*)eg + (size_t)b * PB_BYTES;

    ScanState st;
    if (wv == 1) {
        // ---------- backward: beta = e_199; pairs 1999 down to 1000(hi only) ----------
        st.A0 = 0.0f; st.A1 = 0.0f; st.A2 = 0.0f;
        st.A3 = (lane == 49) ? 1.0f : 0.0f;
        st.S = 0; st.D = 0;
        int off = 1999 * 800 + lidx * 16;
        uint4 wb[NSLOT];
        #pragma unroll
        for (int j = 0; j < NSLOT; ++j) { wb[j] = *(const uint4*)(egb + off); off -= 800; }
        for (int k = 0; k < 49; ++k) {
            #pragma unroll
            for (int j = 0; j < NSLOT; ++j) {
                if ((j & 3) == 0) brenorm(st);
                uint4 w = wb[j];
                wb[j] = *(const uint4*)(egb + off); off -= 800;
                bstep(st, LO(w.z), HI(w.z), LO(w.w), HI(w.w));   // t = 2p+1 first
                bstep(st, LO(w.x), HI(w.x), LO(w.y), HI(w.y));   // then t = 2p
            }
        }
        #pragma unroll
        for (int j = 0; j < NSLOT; ++j) {      // pairs 1019..1001 full, 1000 hi-only
            if ((j & 3) == 0) brenorm(st);
            uint4 w = wb[j];
            bstep(st, LO(w.z), HI(w.z), LO(w.w), HI(w.w));
            if (j < NSLOT - 1) bstep(st, LO(w.x), HI(w.x), LO(w.y), HI(w.y));
        }
        brenorm(st);
        jb0[lane] = st.A0; jb1[lane] = st.A1; jb2[lane] = st.A2; jb3[lane] = st.A3;
        jsb[lane] = st.S;
    } else {
        // ---------- forward: alpha_0 -> t=1 (pair0 hi) -> pairs 1..999 -> pair1000 lo ----------
        st = scan_init(in, tgt, lane, b);
        int off = 800 + lidx * 16;
        uint4 wb[NSLOT];
        #pragma unroll
        for (int j = 0; j < NSLOT; ++j) { wb[j] = *(const uint4*)(egb + off); off += 800; }
        uint2 h0 = *(const uint2*)(egb + lidx * 16 + 8);
        step(st, LO(h0.x), HI(h0.x), LO(h0.y), HI(h0.y));        // t = 1
        for (int k = 0; k < 49; ++k) {
            #pragma unroll
            for (int j = 0; j < NSLOT; ++j) {
                if ((j & 3) == 0) renorm(st, lane);
                uint4 w = wb[j];
                wb[j] = *(const uint4*)(egb + off); off += 800;
                step(st, LO(w.x), HI(w.x), LO(w.y), HI(w.y));    // t = 2p
                step(st, LO(w.z), HI(w.z), LO(w.w), HI(w.w));    // t = 2p+1
            }
        }
        #pragma unroll
        for (int j = 0; j < NSLOT; ++j) {      // pairs 981..999 full, 1000 lo-only
            if ((j & 3) == 0) renorm(st, lane);
            uint4 w = wb[j];
            step(st, LO(w.x), HI(w.x), LO(w.y), HI(w.y));
            if (j < NSLOT - 1) step(st, LO(w.z), HI(w.z), LO(w.w), HI(w.w));
        }
        renorm(st, lane);
    }
    __syncthreads();
    if (wv == 0) {
        // junction: log2( sum_u alpha_2000[u] * beta_2001[u] )
        float d = st.A0 * jb0[lane] + st.A1 * jb1[lane]
                + st.A2 * jb2[lane] + st.A3 * jb3[lane];
        float ll = (lane < 50) ? hw_log2(fmaxf(d, 1e-38f)) + (float)(st.S + jsb[lane])
                               : -1e30f;
        float mx = ll;
        #pragma unroll
        for (int o = 32; o > 0; o >>= 1) mx = fmaxf(mx, __shfl_xor(mx, o));
        float s = (lane < 50) ? hw_exp2(ll - mx) : 0.0f;
        #pragma unroll
        for (int o = 32; o > 0; o >>= 1) s += __shfl_xor(s, o);
        if (lane == 0) atomicAdd(out, -(mx + hw_log2(s)) * (LN2 / 64.0f));
    }
}

// ---- fallback pair (no-workspace path; R7-proven forward core) ----
__global__ __launch_bounds__(256) void lse_sum_kernel(const float* __restrict__ in,
                                                      float* __restrict__ out) {
    const int lane = threadIdx.x & 63;
    const int w = threadIdx.x >> 6;
    const int wid = blockIdx.x * 4 + w;
    const int ROWS = (T_DIM * B_DIM) / 1024;
    const float* p = in + (size_t)wid * ROWS * 64 + lane;
    float acc = 0.0f;
    for (int i = 0; i < ROWS; i += 2) {
        float xa = p[(size_t)i * 64];
        float xb = p[(size_t)(i + 1) * 64];
        float ea = hw_exp2(xa * LOG2E);
        float eb = hw_exp2(xb * LOG2E);
        #pragma unroll
        for (int off = 32; off > 0; off >>= 1) {
            ea += __shfl_xor(ea, off);
            eb += __shfl_xor(eb, off);
        }
        acc += hw_log2(ea) + hw_log2(eb);
    }
    __shared__ float red[4];
    if (lane == 0) red[w] = acc;
    __syncthreads();
    if (threadIdx.x == 0)
        atomicAdd(out, (red[0] + red[1] + red[2] + red[3]) * (LN2 / 64.0f));
}

__global__ __launch_bounds__(64) void scan_fb(const float* __restrict__ in,
                                              const int* __restrict__ tgt,
                                              float* __restrict__ out) {
    const int lane = threadIdx.x;
    const int b = blockIdx.x;
    const int lidx = (lane < 50) ? lane : 49;
    int4 tg = ((const int4*)(tgt + b * U_DIM))[lidx];
    tg.x &= 63; tg.y &= 63; tg.z &= 63; tg.w &= 63;
    ScanState st = scan_init(in, tgt, lane, b);
    const char* inb = (const char*)in;
    int o0 = 16384 + b * 256 + tg.x * 4;
    int o1 = 16384 + b * 256 + tg.y * 4;
    int o2 = 16384 + b * 256 + tg.z * 4;
    int o3 = 16384 + b * 256 + tg.w * 4;
    const int m0 = 3999 * 16384 + b * 256 + tg.x * 4;
    const int m1 = m0 + (tg.y - tg.x) * 4;
    const int m2 = m0 + (tg.z - tg.x) * 4;
    const int m3 = m0 + (tg.w - tg.x) * 4;
    float f0[16], f1[16], f2[16], f3[16];
    #pragma unroll
    for (int j = 0; j < 16; ++j) {
        f0[j] = *(const float*)(inb + min(o0, m0)); o0 += 16384;
        f1[j] = *(const float*)(inb + min(o1, m1)); o1 += 16384;
        f2[j] = *(const float*)(inb + min(o2, m2)); o2 += 16384;
        f3[j] = *(const float*)(inb + min(o3, m3)); o3 += 16384;
    }
    for (int k = 0; k < 249; ++k) {
        #pragma unroll
        for (int j = 0; j < 16; ++j) {
            if (j == 0 || j == 8) renorm(st, lane);
            float e0 = hw_exp2(f0[j] * LOG2E);
            float e1 = hw_exp2(f1[j] * LOG2E);
            float e2 = hw_exp2(f2[j] * LOG2E);
            float e3 = hw_exp2(f3[j] * LOG2E);
            f0[j] = *(const float*)(inb + min(o0, m0)); o0 += 16384;
            f1[j] = *(const float*)(inb + min(o1, m1)); o1 += 16384;
            f2[j] = *(const float*)(inb + min(o2, m2)); o2 += 16384;
            f3[j] = *(const float*)(inb + min(o3, m3)); o3 += 16384;
            step(st, e0, e1, e2, e3);
        }
    }
    #pragma unroll
    for (int j = 0; j < 15; ++j) {
        if (j == 0 || j == 8) renorm(st, lane);
        float e0 = hw_exp2(f0[j] * LOG2E);
        float e1 = hw_exp2(f1[j] * LOG2E);
        float e2 = hw_exp2(f2[j] * LOG2E);
        float e3 = hw_exp2(f3[j] * LOG2E);
        step(st, e0, e1, e2, e3);
    }
    if (lane == 49) {
        float a2 = hw_log2(fmaxf(st.A3, 1e-38f)) + (float)st.S;
        atomicAdd(out, -a2 * (LN2 / 64.0f));
    }
}

extern "C" void kernel_launch(void* const* d_in, const int* in_sizes, int n_in,
                              void* d_out, int out_size, void* d_ws, size_t ws_size,
                              hipStream_t stream) {
    const float* inputs = (const float*)d_in[0];   // (T, B, C) fp32
    const int* targets = (const int*)d_in[1];      // (B, U) int32
    float* out = (float*)d_out;                    // scalar fp32

    (void)hipMemsetAsync(out, 0, sizeof(float), stream);

    const size_t eg_bytes = (size_t)B_DIM * PB_BYTES;   // 102.4 MB
    if (ws_size >= eg_bytes) {
        unsigned* eg = (unsigned*)d_ws;
        prep_kernel<<<2000, 256, 0, stream>>>(inputs, targets, eg, out);
        scan2_kernel<<<B_DIM, 128, 0, stream>>>(inputs, targets, eg, out);
    } else {
        scan_fb<<<B_DIM, 64, 0, stream>>>(inputs, targets, out);
        lse_sum_kernel<<<256, 256, 0, stream>>>(inputs, out);
    }
}